// Round 1
// baseline (145.463 us; speedup 1.0000x reference)
//
#include <hip/hip_runtime.h>

#define NI 4096
#define NH 8192
#define NO 2048

__device__ __forceinline__ float apply_act(float x, int id) {
    switch (id) {
        case 0:  return x;
        case 1:  return x >= 0.f ? x : 0.01f * x;   // leaky_relu
        case 2:  return fmaxf(x, 0.f);              // relu
        case 3:  return 1.f / (1.f + expf(-x));     // sigmoid
        default: return tanhf(x);                   // tanh
    }
}

// One 64-lane wave computes dot(Wrow, x) over K elements with float4 loads.
// Result valid in all lanes (butterfly reduce).
__device__ __forceinline__ float wave_dot(const float* __restrict__ Wrow,
                                          const float* __restrict__ x,
                                          int K, int lane) {
    const float4* __restrict__ W4 = (const float4*)Wrow;
    const float4* __restrict__ x4 = (const float4*)x;
    float acc = 0.f;
    const int n4 = K >> 2;
    #pragma unroll 4
    for (int i = lane; i < n4; i += 64) {
        float4 w = W4[i];
        float4 v = x4[i];
        acc = fmaf(w.x, v.x, acc);
        acc = fmaf(w.y, v.y, acc);
        acc = fmaf(w.z, v.z, acc);
        acc = fmaf(w.w, v.w, acc);
    }
    #pragma unroll
    for (int off = 32; off; off >>= 1) acc += __shfl_xor(acc, off, 64);
    return acc;
}

// flags[0] = any(inputs!=0), flags[1] = any(activs0!=0), flags[2] = any(outputs0!=0)
__global__ __launch_bounds__(256) void k_flags(const float* __restrict__ xin,
                                               const float* __restrict__ a0,
                                               const float* __restrict__ o0,
                                               int* __restrict__ flags) {
    int tid = blockIdx.x * 256 + threadIdx.x;
    int stride = gridDim.x * 256;
    int f0 = 0, f1 = 0, f2 = 0;
    for (int i = tid; i < NI; i += stride) f0 |= (xin[i] != 0.f);
    for (int i = tid; i < NH; i += stride) f1 |= (a0[i]  != 0.f);
    for (int i = tid; i < NO; i += stride) f2 |= (o0[i]  != 0.f);
    if (f0) atomicOr(flags + 0, 1);
    if (f1) atomicOr(flags + 1, 1);
    if (f2) atomicOr(flags + 2, 1);
}

// c_h[m] = dot(W_i2h[m,:], inputs) + dot(W_o2h[m,:], outputs0)   (loop-invariant)
__global__ __launch_bounds__(256) void k_const_h(const float* __restrict__ W_i2h,
                                                 const float* __restrict__ W_o2h,
                                                 const float* __restrict__ xin,
                                                 const float* __restrict__ o0,
                                                 const int* __restrict__ flags,
                                                 float* __restrict__ c_h) {
    int wave = threadIdx.x >> 6;
    int lane = threadIdx.x & 63;
    int m = blockIdx.x * 4 + wave;
    float dot = 0.f;
    if (flags[0]) dot += wave_dot(W_i2h + (size_t)m * NI, xin, NI, lane);
    if (flags[2]) dot += wave_dot(W_o2h + (size_t)m * NO, o0,  NO, lane);
    if (lane == 0) c_h[m] = dot;
}

// out[m] = act( resp[m] * (c_h[m] + dot(W_h2h[m,:], x)) + bias[m], ids[m] )
// If flag != nullptr and *flag == 0, x is all-zero: skip the entire W_h2h read.
__global__ __launch_bounds__(256) void k_step(const float* __restrict__ W_h2h,
                                              const float* __restrict__ x,
                                              const float* __restrict__ c_h,
                                              const float* __restrict__ resp,
                                              const float* __restrict__ bias,
                                              const int* __restrict__ ids,
                                              const int* __restrict__ flag,
                                              float* __restrict__ out) {
    int wave = threadIdx.x >> 6;
    int lane = threadIdx.x & 63;
    int m = blockIdx.x * 4 + wave;
    float dot = 0.f;
    if (!flag || flag[0]) dot = wave_dot(W_h2h + (size_t)m * NH, x, NH, lane);
    if (lane == 0) {
        float pre = fmaf(resp[m], c_h[m] + dot, bias[m]);
        out[m] = apply_act(pre, ids[m]);
    }
}

// out[m] = act( o_resp[m] * (i2o + o2o + h2o) + o_bias[m], o_ids[m] )
__global__ __launch_bounds__(256) void k_final(const float* __restrict__ W_i2o,
                                               const float* __restrict__ W_o2o,
                                               const float* __restrict__ W_h2o,
                                               const float* __restrict__ xin,
                                               const float* __restrict__ o0,
                                               const float* __restrict__ act,
                                               const float* __restrict__ resp,
                                               const float* __restrict__ bias,
                                               const int* __restrict__ ids,
                                               const int* __restrict__ flags,
                                               float* __restrict__ out) {
    int wave = threadIdx.x >> 6;
    int lane = threadIdx.x & 63;
    int m = blockIdx.x * 4 + wave;
    float dot = wave_dot(W_h2o + (size_t)m * NH, act, NH, lane);
    if (flags[0]) dot += wave_dot(W_i2o + (size_t)m * NI, xin, NI, lane);
    if (flags[2]) dot += wave_dot(W_o2o + (size_t)m * NO, o0,  NO, lane);
    if (lane == 0) {
        float pre = fmaf(resp[m], dot, bias[m]);
        out[m] = apply_act(pre, ids[m]);
    }
}

extern "C" void kernel_launch(void* const* d_in, const int* in_sizes, int n_in,
                              void* d_out, int out_size, void* d_ws, size_t ws_size,
                              hipStream_t stream) {
    const float* inputs   = (const float*)d_in[0];
    const float* W_i2h    = (const float*)d_in[1];
    const float* W_h2h    = (const float*)d_in[2];
    const float* W_o2h    = (const float*)d_in[3];
    const float* W_i2o    = (const float*)d_in[4];
    const float* W_h2o    = (const float*)d_in[5];
    const float* W_o2o    = (const float*)d_in[6];
    const float* h_resp   = (const float*)d_in[7];
    const float* h_bias   = (const float*)d_in[8];
    const float* o_resp   = (const float*)d_in[9];
    const float* o_bias   = (const float*)d_in[10];
    const float* activs0  = (const float*)d_in[11];
    const float* outputs0 = (const float*)d_in[12];
    const int*   h_ids    = (const int*)d_in[13];
    const int*   o_ids    = (const int*)d_in[14];

    float* ws    = (float*)d_ws;
    float* c_h   = ws;            // NH floats
    float* act_a = ws + NH;       // NH floats
    float* act_b = ws + 2 * NH;   // NH floats
    int*   flags = (int*)(ws + 3 * NH);

    hipMemsetAsync(flags, 0, 3 * sizeof(int), stream);
    k_flags<<<32, 256, 0, stream>>>(inputs, activs0, outputs0, flags);

    // loop-invariant part of hidden pre-activation
    k_const_h<<<NH / 4, 256, 0, stream>>>(W_i2h, W_o2h, inputs, outputs0, flags, c_h);

    // step 1: x = activs0 (skip W_h2h entirely if activs0 == 0)
    k_step<<<NH / 4, 256, 0, stream>>>(W_h2h, activs0, c_h, h_resp, h_bias, h_ids,
                                       flags + 1, act_a);
    // step 2
    k_step<<<NH / 4, 256, 0, stream>>>(W_h2h, act_a, c_h, h_resp, h_bias, h_ids,
                                       nullptr, act_b);
    // step 3
    k_step<<<NH / 4, 256, 0, stream>>>(W_h2h, act_b, c_h, h_resp, h_bias, h_ids,
                                       nullptr, act_a);

    // output layer
    k_final<<<NO / 4, 256, 0, stream>>>(W_i2o, W_o2o, W_h2o, inputs, outputs0, act_a,
                                        o_resp, o_bias, o_ids, flags, (float*)d_out);
}

// Round 2
// 134.380 us; speedup vs baseline: 1.0825x; 1.0825x over previous
//
#include <hip/hip_runtime.h>

#define NI 4096
#define NH 8192
#define NO 2048

typedef float f4 __attribute__((ext_vector_type(4)));

__device__ __forceinline__ float apply_act(float x, int id) {
    switch (id) {
        case 0:  return x;
        case 1:  return x >= 0.f ? x : 0.01f * x;   // leaky_relu
        case 2:  return fmaxf(x, 0.f);              // relu
        case 3:  return 1.f / (1.f + expf(-x));     // sigmoid
        default: return tanhf(x);                   // tanh
    }
}

// One 64-lane wave computes dot(Wrow, x). NT: non-temporal weight loads
// (single-use streams must not evict W_h2h from the 256 MiB L3).
template <bool NT>
__device__ __forceinline__ float wave_dot(const float* __restrict__ Wrow,
                                          const float* __restrict__ x,
                                          int K, int lane) {
    const f4* __restrict__ W4 = (const f4*)Wrow;
    const f4* __restrict__ x4 = (const f4*)x;
    float acc = 0.f;
    const int n4 = K >> 2;
    #pragma unroll 4
    for (int i = lane; i < n4; i += 64) {
        f4 w = NT ? __builtin_nontemporal_load(W4 + i) : W4[i];
        f4 v = x4[i];
        acc = fmaf(w.x, v.x, acc);
        acc = fmaf(w.y, v.y, acc);
        acc = fmaf(w.z, v.z, acc);
        acc = fmaf(w.w, v.w, acc);
    }
    #pragma unroll
    for (int off = 32; off; off >>= 1) acc += __shfl_xor(acc, off, 64);
    return acc;
}

// Single block: flags[0]=any(inputs!=0), flags[1]=any(activs0!=0), flags[2]=any(outputs0!=0)
__global__ __launch_bounds__(256) void k_flags(const float* __restrict__ xin,
                                               const float* __restrict__ a0,
                                               const float* __restrict__ o0,
                                               int* __restrict__ flags) {
    __shared__ int s[3];
    int t = threadIdx.x;
    if (t < 3) s[t] = 0;
    __syncthreads();
    int f0 = 0, f1 = 0, f2 = 0;
    for (int i = t; i < NI; i += 256) f0 |= (xin[i] != 0.f);
    for (int i = t; i < NH; i += 256) f1 |= (a0[i]  != 0.f);
    for (int i = t; i < NO; i += 256) f2 |= (o0[i]  != 0.f);
    if (f0) atomicOr(&s[0], 1);
    if (f1) atomicOr(&s[1], 1);
    if (f2) atomicOr(&s[2], 1);
    __syncthreads();
    if (t < 3) flags[t] = s[t];
}

// Fused: c_h[m] = i2h·x + o2h·o0 (loop-invariant), plus step-1 epilogue.
// When activs0==0 (flags[1]==0) step 1's W_h2h dot is zero, so act_a is
// just act(resp*c_h + bias) — free here. Otherwise do the full dot.
__global__ __launch_bounds__(256) void k_h_init(const float* __restrict__ W_i2h,
                                                const float* __restrict__ W_o2h,
                                                const float* __restrict__ W_h2h,
                                                const float* __restrict__ xin,
                                                const float* __restrict__ o0,
                                                const float* __restrict__ a0,
                                                const float* __restrict__ resp,
                                                const float* __restrict__ bias,
                                                const int* __restrict__ ids,
                                                const int* __restrict__ flags,
                                                float* __restrict__ c_h,
                                                float* __restrict__ act_a) {
    int wave = threadIdx.x >> 6;
    int lane = threadIdx.x & 63;
    int m = blockIdx.x * 4 + wave;
    float c = 0.f;
    if (flags[0]) c += wave_dot<true>(W_i2h + (size_t)m * NI, xin, NI, lane);
    if (flags[2]) c += wave_dot<true>(W_o2h + (size_t)m * NO, o0,  NO, lane);
    float d = 0.f;
    if (flags[1]) d = wave_dot<false>(W_h2h + (size_t)m * NH, a0, NH, lane);
    if (lane == 0) {
        c_h[m] = c;
        act_a[m] = apply_act(fmaf(resp[m], c + d, bias[m]), ids[m]);
    }
}

// Hidden step: out[m] = act(resp[m]*(c_h[m] + W_h2h[m,:]·x) + bias[m]).
// REV=1 reverses the block→row mapping so the re-read of W_h2h traverses the
// L3 (256 MiB == sizeof(W_h2h)) in anti-LRU order → maximal hit rate.
template <int REV>
__global__ __launch_bounds__(256) void k_step(const float* __restrict__ W_h2h,
                                              const float* __restrict__ x,
                                              const float* __restrict__ c_h,
                                              const float* __restrict__ resp,
                                              const float* __restrict__ bias,
                                              const int* __restrict__ ids,
                                              float* __restrict__ out) {
    int wave = threadIdx.x >> 6;
    int lane = threadIdx.x & 63;
    int m = blockIdx.x * 4 + wave;
    if (REV) m = (NH - 1) - m;
    float dot = wave_dot<false>(W_h2h + (size_t)m * NH, x, NH, lane);
    if (lane == 0) {
        float pre = fmaf(resp[m], c_h[m] + dot, bias[m]);
        out[m] = apply_act(pre, ids[m]);
    }
}

// Output layer: all weights single-use -> non-temporal.
__global__ __launch_bounds__(256) void k_final(const float* __restrict__ W_i2o,
                                               const float* __restrict__ W_o2o,
                                               const float* __restrict__ W_h2o,
                                               const float* __restrict__ xin,
                                               const float* __restrict__ o0,
                                               const float* __restrict__ act,
                                               const float* __restrict__ resp,
                                               const float* __restrict__ bias,
                                               const int* __restrict__ ids,
                                               const int* __restrict__ flags,
                                               float* __restrict__ out) {
    int wave = threadIdx.x >> 6;
    int lane = threadIdx.x & 63;
    int m = blockIdx.x * 4 + wave;
    float dot = wave_dot<true>(W_h2o + (size_t)m * NH, act, NH, lane);
    if (flags[0]) dot += wave_dot<true>(W_i2o + (size_t)m * NI, xin, NI, lane);
    if (flags[2]) dot += wave_dot<true>(W_o2o + (size_t)m * NO, o0,  NO, lane);
    if (lane == 0) {
        float pre = fmaf(resp[m], dot, bias[m]);
        out[m] = apply_act(pre, ids[m]);
    }
}

extern "C" void kernel_launch(void* const* d_in, const int* in_sizes, int n_in,
                              void* d_out, int out_size, void* d_ws, size_t ws_size,
                              hipStream_t stream) {
    const float* inputs   = (const float*)d_in[0];
    const float* W_i2h    = (const float*)d_in[1];
    const float* W_h2h    = (const float*)d_in[2];
    const float* W_o2h    = (const float*)d_in[3];
    const float* W_i2o    = (const float*)d_in[4];
    const float* W_h2o    = (const float*)d_in[5];
    const float* W_o2o    = (const float*)d_in[6];
    const float* h_resp   = (const float*)d_in[7];
    const float* h_bias   = (const float*)d_in[8];
    const float* o_resp   = (const float*)d_in[9];
    const float* o_bias   = (const float*)d_in[10];
    const float* activs0  = (const float*)d_in[11];
    const float* outputs0 = (const float*)d_in[12];
    const int*   h_ids    = (const int*)d_in[13];
    const int*   o_ids    = (const int*)d_in[14];

    float* ws    = (float*)d_ws;
    float* c_h   = ws;            // NH floats
    float* act_a = ws + NH;       // NH floats
    float* act_b = ws + 2 * NH;   // NH floats
    int*   flags = (int*)(ws + 3 * NH);

    k_flags<<<1, 256, 0, stream>>>(inputs, activs0, outputs0, flags);

    // c_h + step 1 fused
    k_h_init<<<NH / 4, 256, 0, stream>>>(W_i2h, W_o2h, W_h2h, inputs, outputs0,
                                         activs0, h_resp, h_bias, h_ids, flags,
                                         c_h, act_a);
    // step 2 (forward order: fills L3 with W_h2h)
    k_step<0><<<NH / 4, 256, 0, stream>>>(W_h2h, act_a, c_h, h_resp, h_bias, h_ids,
                                          act_b);
    // step 3 (reverse order: anti-LRU traversal -> L3 hits)
    k_step<1><<<NH / 4, 256, 0, stream>>>(W_h2h, act_b, c_h, h_resp, h_bias, h_ids,
                                          act_a);

    // output layer
    k_final<<<NO / 4, 256, 0, stream>>>(W_i2o, W_o2o, W_h2o, inputs, outputs0, act_a,
                                        o_resp, o_bias, o_ids, flags, (float*)d_out);
}